// Round 1
// baseline (112.934 us; speedup 1.0000x reference)
//
#include <hip/hip_runtime.h>

// GATLayer reduces to out = x @ W^T:
//   out = einsum('bnjh,bnhd->bnhd', alpha, h); j appears only in alpha,
//   and softmax over j sums to 1 (self-edge guarantees a finite row)
//   => out = h = x @ W^T, for ANY adj / a_w (both numerically dead).
// B=4, N=2048, IN=256, OUT=256.
//
// Error-compensated bf16 MFMA (Ootomo split): x = xh+xl, W = Wh+Wl (bf16),
// acc += xh*Wh + xh*Wl + xl*Wh  -> ~2^-17 relative error, scale-robust
// (the timing-phase re-poisoned inputs broke the single-pass bf16 version:
//  absmax scaled with |h| past the fixed threshold).
//
// 512 blocks x 256 threads, 16 rows/block (2 blocks/CU, 2 waves/SIMD).
// x staged fp32->bf16(hi,lo) in LDS; W loaded fp32 from global (L2-resident)
// and split in-register via v_cvt_pk_bf16_f32 (1 inst / 2 elems).

typedef __attribute__((ext_vector_type(8))) short short8;
typedef __attribute__((ext_vector_type(4))) float floatx4;
typedef __attribute__((ext_vector_type(4))) int intx4;

__device__ inline int cvtpk_bf16(float a, float b) {
    // dst.lo16 = bf16(a), dst.hi16 = bf16(b), RNE (HW default round mode)
    int r;
    asm("v_cvt_pk_bf16_f32 %0, %1, %2" : "=v"(r) : "v"(a), "v"(b));
    return r;
}
__device__ inline float lo_bf2f(int p) { return __uint_as_float((unsigned)p << 16); }
__device__ inline float hi_bf2f(int p) { return __uint_as_float((unsigned)p & 0xffff0000u); }

#define LSTR 264  // 256 + 8 shorts: 16B-aligned rows, worst bank aliasing 2-way (free)

__global__ __launch_bounds__(256) void gat_gemm(const float* __restrict__ X,
                                                const float* __restrict__ W,
                                                float* __restrict__ out) {
    __shared__ short xh[16 * LSTR];
    __shared__ short xl[16 * LSTR];

    const int r0 = blockIdx.x * 16;   // global row base (b*N + n flattened)
    const int t  = threadIdx.x;

    // Stage 16 rows x 256 f (fp32 -> bf16 hi+lo). 1024 float4 loads, 4/thread.
    const float4* X4 = (const float4*)(X + (size_t)r0 * 256);
    #pragma unroll
    for (int k = 0; k < 4; ++k) {
        int idx = t + 256 * k;          // 0..1023
        int row = idx >> 6;             // 64 float4 per row
        int c4  = idx & 63;
        float4 v = X4[idx];
        int h0 = cvtpk_bf16(v.x, v.y);
        int h1 = cvtpk_bf16(v.z, v.w);
        int l0 = cvtpk_bf16(v.x - lo_bf2f(h0), v.y - hi_bf2f(h0));
        int l1 = cvtpk_bf16(v.z - lo_bf2f(h1), v.w - hi_bf2f(h1));
        *(int2*)&xh[row * LSTR + c4 * 4] = make_int2(h0, h1);
        *(int2*)&xl[row * LSTR + c4 * 4] = make_int2(l0, l1);
    }
    __syncthreads();

    const int lane = t & 63;
    const int wave = t >> 6;            // 4 waves, wave w -> out cols [w*64, w*64+64)
    const int q    = lane >> 4;         // k-group (0..3)
    const int m    = lane & 15;         // A-row / B-col index
    const int o0   = wave * 64;

    floatx4 acc[4] = {};                // [n-tile]

    #pragma unroll
    for (int it = 0; it < 8; ++it) {
        const int f0 = it * 32 + q * 8;
        // A fragments (hi, lo): A[m][k], k = q*8 + e
        short8 ah = *(const short8*)&xh[m * LSTR + f0];
        short8 al = *(const short8*)&xl[m * LSTR + f0];
        #pragma unroll
        for (int nt = 0; nt < 4; ++nt) {
            // B fragment: B[k][n] = W[o0+nt*16+m][f0+k], fp32 -> bf16 hi+lo
            const float* wp = W + (size_t)(o0 + nt * 16 + m) * 256 + f0;
            float4 w0 = *(const float4*)wp;
            float4 w1 = *(const float4*)(wp + 4);
            int bh0 = cvtpk_bf16(w0.x, w0.y);
            int bh1 = cvtpk_bf16(w0.z, w0.w);
            int bh2 = cvtpk_bf16(w1.x, w1.y);
            int bh3 = cvtpk_bf16(w1.z, w1.w);
            int bl0 = cvtpk_bf16(w0.x - lo_bf2f(bh0), w0.y - hi_bf2f(bh0));
            int bl1 = cvtpk_bf16(w0.z - lo_bf2f(bh1), w0.w - hi_bf2f(bh1));
            int bl2 = cvtpk_bf16(w1.x - lo_bf2f(bh2), w1.y - hi_bf2f(bh2));
            int bl3 = cvtpk_bf16(w1.z - lo_bf2f(bh3), w1.w - hi_bf2f(bh3));
            short8 bh = __builtin_bit_cast(short8, (intx4){bh0, bh1, bh2, bh3});
            short8 bl = __builtin_bit_cast(short8, (intx4){bl0, bl1, bl2, bl3});
            acc[nt] = __builtin_amdgcn_mfma_f32_16x16x32_bf16(ah, bh, acc[nt], 0, 0, 0);
            acc[nt] = __builtin_amdgcn_mfma_f32_16x16x32_bf16(ah, bl, acc[nt], 0, 0, 0);
            acc[nt] = __builtin_amdgcn_mfma_f32_16x16x32_bf16(al, bh, acc[nt], 0, 0, 0);
        }
    }

    // C/D layout: col = lane&15, row = (lane>>4)*4 + reg  (verified m89/m91)
    #pragma unroll
    for (int nt = 0; nt < 4; ++nt) {
        #pragma unroll
        for (int reg = 0; reg < 4; ++reg) {
            int row = r0 + q * 4 + reg;
            int col = o0 + nt * 16 + m;
            out[(size_t)row * 256 + col] = acc[nt][reg];
        }
    }
}

extern "C" void kernel_launch(void* const* d_in, const int* in_sizes, int n_in,
                              void* d_out, int out_size, void* d_ws, size_t ws_size,
                              hipStream_t stream) {
    const float* x = (const float*)d_in[0];   // [4][2048][256] fp32
    // d_in[1] = adj (dead), d_in[3] = a_w (dead)
    const float* W = (const float*)d_in[2];   // [256][256] fp32
    float* out     = (float*)d_out;           // [4][2048][256] fp32

    gat_gemm<<<512, 256, 0, stream>>>(x, W, out);
}